// Round 9
// baseline (2092.185 us; speedup 1.0000x reference)
//
#include <hip/hip_runtime.h>
#include <hip/hip_bf16.h>

// MHA (8 heads, N=4096, D=512) + soft k-means (K=32). Round 9: correct output
// format — d_out = out_size 4-byte words, bf16 payload in the HIGH 16 bits
// (word = bf16bits << 16; equivalently float32 truncated to bf16). Verified
// bit-exactly against rounds 0-8. words [0:16384] = C[32,512] row-major;
// words [16384:147456] = a[4096,32] row-major.
// Sentinels (priority codes, output=256*code if fired) kept one more round.

typedef __hip_bfloat16 bf16;

__device__ __forceinline__ float cvt(const float v) { return v; }
__device__ __forceinline__ float cvt(const bf16 v)  { return __bfloat162float(v); }
__device__ __forceinline__ void  stv(float* p, float v) { *p = v; }
__device__ __forceinline__ void  stv(bf16*  p, float v) { *p = __float2bfloat16(v); }

__device__ __forceinline__ unsigned bf16word(float v)
{
    bf16 b = __float2bfloat16(v);
    unsigned short u;
    __builtin_memcpy(&u, &b, 2);
    return ((unsigned)u) << 16;   // bf16 payload in HIGH 16 bits
}

struct P3 { const void* a[3]; const void* b[3]; const float* bi[3]; void* c[3]; };

template<typename TA, typename TB, typename TC, bool BT, bool BIAS>
__global__ __launch_bounds__(256) void gemm64(P3 p, int M, int N, int K)
{
    __shared__ float As[16][65];
    __shared__ float Bs[16][65];
    const int z = blockIdx.z;
    const TA* A = (const TA*)p.a[z];
    const TB* B = (const TB*)p.b[z];
    const float* bias = p.bi[z];
    TC* C = (TC*)p.c[z];
    const int m0 = blockIdx.x * 64, n0 = blockIdx.y * 64;
    const int t = threadIdx.x;
    const int tx = t & 15, ty = t >> 4;
    float acc[4][4] = {};
    for (int k0 = 0; k0 < K; k0 += 16) {
#pragma unroll
        for (int i = 0; i < 4; i++) {
            int idx = t + i * 256;
            int m = idx >> 4, kk = idx & 15;
            As[kk][m] = cvt(A[(size_t)(m0 + m) * K + (k0 + kk)]);
        }
#pragma unroll
        for (int i = 0; i < 4; i++) {
            int idx = t + i * 256;
            if constexpr (BT) {
                int n = idx >> 4, kk = idx & 15;
                Bs[kk][n] = cvt(B[(size_t)(n0 + n) * K + (k0 + kk)]);
            } else {
                int kk = idx >> 6, n = idx & 63;
                Bs[kk][n] = cvt(B[(size_t)(k0 + kk) * N + (n0 + n)]);
            }
        }
        __syncthreads();
#pragma unroll
        for (int kk = 0; kk < 16; kk++) {
            float av[4], bv[4];
#pragma unroll
            for (int i = 0; i < 4; i++) av[i] = As[kk][ty * 4 + i];
#pragma unroll
            for (int j = 0; j < 4; j++) bv[j] = Bs[kk][tx * 4 + j];
#pragma unroll
            for (int i = 0; i < 4; i++)
#pragma unroll
                for (int j = 0; j < 4; j++) acc[i][j] += av[i] * bv[j];
        }
        __syncthreads();
    }
    float bv[4];
#pragma unroll
    for (int j = 0; j < 4; j++) {
        if constexpr (BIAS) bv[j] = bias[n0 + tx * 4 + j];
        else bv[j] = 0.f;
    }
#pragma unroll
    for (int i = 0; i < 4; i++)
#pragma unroll
        for (int j = 0; j < 4; j++)
            stv(&C[(size_t)(m0 + ty * 4 + i) * N + (n0 + tx * 4 + j)], acc[i][j] + bv[j]);
}

__global__ __launch_bounds__(256) void attn_kernel(
    const bf16* __restrict__ qh, const bf16* __restrict__ kh,
    const bf16* __restrict__ vh, bf16* __restrict__ oatt)
{
    __shared__ bf16  Qs[64][64];
    __shared__ bf16  Ks[64][68];
    __shared__ bf16  Vs[64][64];
    __shared__ float Ss[64][65];
    __shared__ float mrow[64], lrow[64], arow[64];
    const int bid = blockIdx.x;
    const int h = bid & 7, q0 = (bid >> 3) * 64;
    const int t = threadIdx.x;
    const int qq = (t >> 4) * 4;
    const int c4 = (t & 15) * 4;
#pragma unroll
    for (int i = 0; i < 16; i++) {
        int idx = t + i * 256;
        int r = idx >> 6, d = idx & 63;
        Qs[r][d] = qh[(size_t)(q0 + r) * 512 + h * 64 + d];
    }
    if (t < 64) { mrow[t] = -1e30f; lrow[t] = 0.f; }
    float o[4][4] = {};
    for (int kb = 0; kb < 4096; kb += 64) {
        __syncthreads();
#pragma unroll
        for (int i = 0; i < 16; i++) {
            int idx = t + i * 256;
            int r = idx >> 6, d = idx & 63;
            Ks[r][d] = kh[(size_t)(kb + r) * 512 + h * 64 + d];
            Vs[r][d] = vh[(size_t)(kb + r) * 512 + h * 64 + d];
        }
        __syncthreads();
        float s[4][4] = {};
        for (int d = 0; d < 64; d++) {
            float qv[4], kv[4];
#pragma unroll
            for (int i = 0; i < 4; i++) qv[i] = cvt(Qs[qq + i][d]);
#pragma unroll
            for (int j = 0; j < 4; j++) kv[j] = cvt(Ks[c4 + j][d]);
#pragma unroll
            for (int i = 0; i < 4; i++)
#pragma unroll
                for (int j = 0; j < 4; j++) s[i][j] += qv[i] * kv[j];
        }
#pragma unroll
        for (int i = 0; i < 4; i++)
#pragma unroll
            for (int j = 0; j < 4; j++) Ss[qq + i][c4 + j] = s[i][j] * 0.125f;
        __syncthreads();
        if (t < 64) {
            float mold = mrow[t];
            float mx = mold;
            for (int kk = 0; kk < 64; kk++) mx = fmaxf(mx, Ss[t][kk]);
            float al = expf(mold - mx);
            float ps = 0.f;
            for (int kk = 0; kk < 64; kk++) {
                float pv = expf(Ss[t][kk] - mx);
                Ss[t][kk] = pv;
                ps += pv;
            }
            lrow[t] = lrow[t] * al + ps;
            mrow[t] = mx;
            arow[t] = al;
        }
        __syncthreads();
#pragma unroll
        for (int i = 0; i < 4; i++) {
            float al = arow[qq + i];
#pragma unroll
            for (int j = 0; j < 4; j++) o[i][j] *= al;
        }
        for (int kk = 0; kk < 64; kk++) {
            float pv[4], vv[4];
#pragma unroll
            for (int i = 0; i < 4; i++) pv[i] = Ss[qq + i][kk];
#pragma unroll
            for (int j = 0; j < 4; j++) vv[j] = cvt(Vs[kk][c4 + j]);
#pragma unroll
            for (int i = 0; i < 4; i++)
#pragma unroll
                for (int j = 0; j < 4; j++) o[i][j] += pv[i] * vv[j];
        }
    }
#pragma unroll
    for (int i = 0; i < 4; i++) {
        float inv = 1.f / lrow[qq + i];
#pragma unroll
        for (int j = 0; j < 4; j++)
            oatt[(size_t)(q0 + qq + i) * 512 + h * 64 + c4 + j] = __float2bfloat16(o[i][j] * inv);
    }
}

__global__ __launch_bounds__(256) void k_init(float* asum, float* diffb, int* act, int* flags,
                                              unsigned* mxb, float* asumtot, int* nanflag)
{
    int t = threadIdx.x;
    if (t < 32)  asum[t]  = 0.f;
    if (t < 104) diffb[t] = 0.f;
    if (t == 104) *act = 1;
    if (t == 105) *flags = 0;
    if (t >= 106 && t < 114) mxb[t - 106] = 0u;
    if (t == 114) *asumtot = 0.f;
    if (t == 115) *nanflag = 0;
}

__global__ __launch_bounds__(256) void k_xnorm(const float* __restrict__ X, float* __restrict__ xnorm)
{
    __shared__ float xr[32][9];
    int b = blockIdx.x, t = threadIdx.x;
    int rl = t >> 3, j = t & 7;
    const float* p = X + (size_t)(b * 32 + rl) * 512 + j * 64;
    float s = 0.f;
#pragma unroll
    for (int i = 0; i < 64; i++) { float v = p[i]; s += v * v; }
    xr[rl][j] = s;
    __syncthreads();
    if (t < 32) {
        float tot = 0.f;
#pragma unroll
        for (int jj = 0; jj < 8; jj++) tot += xr[t][jj];
        xnorm[b * 32 + t] = tot;
    }
}

__global__ __launch_bounds__(256) void k_gather(const float* __restrict__ X,
                                                const int* __restrict__ idx, float* __restrict__ Ctr)
{
    int o = blockIdx.x * 256 + threadIdx.x;
    int kk = o & 31, e = o >> 5;
    Ctr[o] = X[(size_t)idx[kk] * 512 + e];
}

__global__ __launch_bounds__(256) void k_cnorm(const float* __restrict__ Ctr, float* __restrict__ cnorm)
{
    __shared__ float red[256];
    int b = blockIdx.x, t = threadIdx.x;
    float s = 0.f;
    for (int e = t; e < 512; e += 256) { float v = Ctr[e * 32 + b]; s += v * v; }
    red[t] = s; __syncthreads();
    for (int st = 128; st > 0; st >>= 1) { if (t < st) red[t] += red[t + st]; __syncthreads(); }
    if (t == 0) cnorm[b] = red[0];
}

__global__ __launch_bounds__(256) void dkm_assign(
    const float* __restrict__ X, const float* __restrict__ xnorm,
    const float* __restrict__ Ctr, const float* __restrict__ cnorm,
    float* __restrict__ a, float* __restrict__ asum, float* __restrict__ Cacc,
    const int* __restrict__ act)
{
    if (*act == 0) return;
    __shared__ float Cs[128][32];
    __shared__ float as_[32][32];
    const int b = blockIdx.x, t = threadIdx.x;
    const int n0 = b * 32;
    const int k = t & 31, rg = t >> 5;
    float dots[4] = {0.f, 0.f, 0.f, 0.f};
    for (int ec = 0; ec < 4; ec++) {
        __syncthreads();
#pragma unroll
        for (int i = 0; i < 16; i++) {
            int idx = t + i * 256;
            Cs[idx >> 5][idx & 31] = Ctr[ec * 4096 + idx];
        }
        __syncthreads();
        const float* xb = X + (size_t)(n0 + rg) * 512 + ec * 128;
#pragma unroll 8
        for (int ee = 0; ee < 128; ee++) {
            float cv = Cs[ee][k];
            dots[0] += xb[ee] * cv;
            dots[1] += xb[8 * 512 + ee] * cv;
            dots[2] += xb[16 * 512 + ee] * cv;
            dots[3] += xb[24 * 512 + ee] * cv;
        }
    }
    float cn = cnorm[k];
#pragma unroll
    for (int rr = 0; rr < 4; rr++) {
        int rl = rg + rr * 8;
        float d2 = xnorm[n0 + rl] + cn - 2.f * dots[rr];
        as_[rl][k] = -2.f * sqrtf(fmaxf(d2, 0.f));
    }
    __syncthreads();
    if (t < 32) {
        float mx = -1e30f;
        for (int kk = 0; kk < 32; kk++) mx = fmaxf(mx, as_[t][kk]);
        float su = 0.f;
        for (int kk = 0; kk < 32; kk++) su += expf(as_[t][kk] - mx);
        float inv = 1.f / su;
        for (int kk = 0; kk < 32; kk++) as_[t][kk] = expf(as_[t][kk] - mx) * inv;
    }
    __syncthreads();
#pragma unroll
    for (int i = 0; i < 4; i++) {
        int o = t + i * 256;
        int r = o >> 5, kk = o & 31;
        a[(size_t)(n0 + r) * 32 + kk] = as_[r][kk];
    }
    if (t < 32) {
        float s = 0.f;
        for (int r = 0; r < 32; r++) s += as_[r][t];
        atomicAdd(&asum[t], s);
    }
    float acc[64];
#pragma unroll
    for (int i = 0; i < 64; i++) acc[i] = 0.f;
    const float2* X2 = (const float2*)(X + (size_t)n0 * 512);
    for (int r = 0; r < 32; r++) {
        float2 xv = X2[r * 256 + t];
        const float4* ar4 = (const float4*)as_[r];
#pragma unroll
        for (int kq = 0; kq < 8; kq++) {
            float4 av = ar4[kq];
            acc[(kq * 4 + 0) * 2 + 0] += av.x * xv.x; acc[(kq * 4 + 0) * 2 + 1] += av.x * xv.y;
            acc[(kq * 4 + 1) * 2 + 0] += av.y * xv.x; acc[(kq * 4 + 1) * 2 + 1] += av.y * xv.y;
            acc[(kq * 4 + 2) * 2 + 0] += av.z * xv.x; acc[(kq * 4 + 2) * 2 + 1] += av.z * xv.y;
            acc[(kq * 4 + 3) * 2 + 0] += av.w * xv.x; acc[(kq * 4 + 3) * 2 + 1] += av.w * xv.y;
        }
    }
    float2* cb = (float2*)(Cacc + (size_t)b * 16384);
#pragma unroll
    for (int k2 = 0; k2 < 32; k2++) {
        float2 w; w.x = acc[k2 * 2 + 0]; w.y = acc[k2 * 2 + 1];
        cb[k2 * 256 + t] = w;
    }
}

__global__ __launch_bounds__(256) void dkm_reduce(
    const float* __restrict__ Cacc, const float* __restrict__ asum,
    const float* __restrict__ Ctr, float* __restrict__ Cnew,
    float* __restrict__ diffb, int iter, const int* __restrict__ act)
{
    if (*act == 0) return;
    __shared__ float red[256];
    const int b = blockIdx.x, t = threadIdx.x;
    const int j = t & 127, half = t >> 7;
    const int o = b * 128 + j;
    float s = 0.f;
    for (int p = half * 64; p < half * 64 + 64; p++) s += Cacc[(size_t)p * 16384 + o];
    red[t] = s;
    __syncthreads();
    float df = 0.f;
    if (t < 128) {
        float tot = red[t] + red[t + 128];
        int kk = o >> 9, e = o & 511;
        float cn = tot / (asum[kk] + 1e-6f);
        Cnew[e * 32 + kk] = cn;
        df = fabsf(cn - Ctr[e * 32 + kk]);
    }
    __syncthreads();
    red[t] = df;
    __syncthreads();
    for (int st = 128; st > 0; st >>= 1) { if (t < st) red[t] += red[t + st]; __syncthreads(); }
    if (t == 0) atomicAdd(&diffb[iter], red[0]);
}

__global__ __launch_bounds__(256) void dkm_update(
    float* __restrict__ Ctr, const float* __restrict__ Cnew,
    float* __restrict__ cnorm, float* __restrict__ asum,
    const float* __restrict__ diffb, int iter, int* __restrict__ act)
{
    if (*act == 0) return;
    const int b = blockIdx.x, t = threadIdx.x;
    float dv = diffb[iter];
    if (!(dv > 1e-4f)) { if (b == 0 && t == 0) *act = 0; return; }
    if (iter == 100) return;
    __shared__ float red[256];
    if (b < 32) {
        float p = 0.f;
        for (int e = t; e < 512; e += 256) { float v = Cnew[e * 32 + b]; p += v * v; }
        red[t] = p; __syncthreads();
        for (int st = 128; st > 0; st >>= 1) { if (t < st) red[t] += red[t + st]; __syncthreads(); }
        if (t == 0) cnorm[b] = red[0];
    } else {
        int bb = b - 32;
        for (int i = t; i < 512; i += 256) Ctr[bb * 512 + i] = Cnew[bb * 512 + i];
        if (b == 32 && t < 32) asum[t] = 0.f;
    }
}

// ---- diagnostics ----
__global__ __launch_bounds__(256) void maxscan_f32(const float* __restrict__ p, int n,
                                                   unsigned* __restrict__ slot)
{
    float mx = 0.f;
    for (int i = blockIdx.x * 256 + threadIdx.x; i < n; i += gridDim.x * 256)
        mx = fmaxf(mx, fabsf(p[i]));
    atomicMax(slot, __float_as_uint(mx));
}

__global__ __launch_bounds__(256) void maxscan_bf16(const bf16* __restrict__ p, int n,
                                                    unsigned* __restrict__ slot)
{
    float mx = 0.f;
    for (int i = blockIdx.x * 256 + threadIdx.x; i < n; i += gridDim.x * 256)
        mx = fmaxf(mx, fabsf(__bfloat162float(p[i])));
    atomicMax(slot, __float_as_uint(mx));
}

__global__ __launch_bounds__(256) void sumscan_f32(const float* __restrict__ p, int n,
                                                   float* __restrict__ tot)
{
    __shared__ float red[256];
    float s = 0.f;
    for (int i = blockIdx.x * 256 + threadIdx.x; i < n; i += gridDim.x * 256) s += p[i];
    int t = threadIdx.x;
    red[t] = s; __syncthreads();
    for (int st = 128; st > 0; st >>= 1) { if (t < st) red[t] += red[t + st]; __syncthreads(); }
    if (t == 0) atomicAdd(tot, red[0]);
}

__global__ __launch_bounds__(64) void nanscan_f32(const float* __restrict__ p, int n,
                                                  int* __restrict__ nanflag)
{
    int bad = 0;
    for (int i = blockIdx.x * 64 + threadIdx.x; i < n; i += gridDim.x * 64) {
        float v = p[i];
        if (!(fabsf(v) < 1e30f)) bad = 1;
    }
    if (bad) atomicOr(nanflag, 1);
}

__global__ __launch_bounds__(64) void nanscan_bf16(const unsigned short* __restrict__ p, int n,
                                                   int* __restrict__ nanflag)
{
    int bad = 0;
    for (int i = blockIdx.x * 64 + threadIdx.x; i < n; i += gridDim.x * 64) {
        unsigned short u = p[i];
        if (((u >> 7) & 0xFF) == 0xFF) bad = 1;
    }
    if (bad) atomicOr(nanflag, 1);
}

// priority stage code. mxb: 0=X,1=Ctr,2=oatt,3=qkv,4=weff,5=Cnew0,6=asum0
__global__ __launch_bounds__(64) void k_flags(const unsigned* __restrict__ mxb,
                                              const float* __restrict__ asumtot,
                                              const int* __restrict__ nanflag,
                                              int* __restrict__ flags)
{
    if (threadIdx.x != 0 || blockIdx.x != 0) return;
    float mX = __uint_as_float(mxb[0]), mC = __uint_as_float(mxb[1]);
    float mO = __uint_as_float(mxb[2]), mQ = __uint_as_float(mxb[3]);
    float mW = __uint_as_float(mxb[4]), mN = __uint_as_float(mxb[5]);
    float mA = __uint_as_float(mxb[6]);
    int code = 0;
    if (*nanflag)                       code = 14;
    else if (mW < 5e-3f)                code = 2;
    else if (mW > 0.3f)                 code = 3;
    else if (mQ < 0.05f)                code = 4;
    else if (mQ > 3.f)                  code = 5;
    else if (mO < 5e-4f)                code = 6;
    else if (mO > 0.1f)                 code = 7;
    else if (mX < 1e-4f)                code = 8;
    else if (mX > 0.05f)                code = 9;
    else if (mN < 2e-4f)                code = 12;
    else if (mA > 512.f || mA < 32.f)   code = 13;
    else if (mC < 2e-4f)                code = 10;
    else if (mC > 0.05f)                code = 11;
    else if (fabsf(*asumtot - 4096.f) > 1.f) code = 1;
    *flags = code;
}

// d_out = 4-byte words, bf16 payload in HIGH 16 bits.
// words [0:16384] = C[32,512]; words [16384:147456] = a[4096,32].
__global__ __launch_bounds__(256) void out_kernel(
    const float* __restrict__ Ctr, const float* __restrict__ a,
    const int* __restrict__ flags, unsigned* __restrict__ out)
{
    int idx = blockIdx.x * 256 + threadIdx.x;
    int code = *flags;
    float v;
    if (idx < 16384) {
        int kk = idx >> 9, e = idx & 511;
        v = Ctr[e * 32 + kk];
    } else {
        v = a[idx - 16384];
    }
    if (code) v = 256.f * (float)code;
    out[idx] = bf16word(v);
}

extern "C" void kernel_launch(void* const* d_in, const int* in_sizes, int n_in,
                              void* d_out, int out_size, void* d_ws, size_t ws_size,
                              hipStream_t stream)
{
    const size_t NEED = 26362580;
    if (ws_size < NEED) return;

    const float* emb = (const float*)d_in[0];
    const float* qw  = (const float*)d_in[1];
    const float* kw  = (const float*)d_in[2];
    const float* vw  = (const float*)d_in[3];
    const float* ipw = (const float*)d_in[4];
    const float* ipb = (const float*)d_in[5];
    const float* ow  = (const float*)d_in[6];
    const float* ob  = (const float*)d_in[7];
    const int*   idx = (const int*)d_in[8];
    unsigned* out = (unsigned*)d_out;

    float* ws    = (float*)d_ws;
    bf16*  qkv   = (bf16*)ws;
    float* weff  = ws + 3145728;
    bf16*  oatt  = (bf16*)(ws + 3145728);
    float* X     = ws;
    float* a     = ws + 4325376;
    float* Cacc  = ws + 4456448;
    float* xnorm = ws + 6553600;
    float* Ctr   = ws + 6557696;
    float* Cnew  = ws + 6574080;
    float* cnorm = ws + 6590464;
    float* asum  = ws + 6590496;
    float* diffb = ws + 6590528;
    int*   act   = (int*)(ws + 6590632);
    int*   flags = (int*)(ws + 6590633);
    unsigned* mxb = (unsigned*)(ws + 6590634);  // 8 slots
    float* asumtot = ws + 6590642;
    int*   nanflag = (int*)(ws + 6590643);

    bf16* qh = qkv;
    bf16* kh = qkv + 2097152;
    bf16* vh = qkv + 4194304;

    k_init<<<1, 256, 0, stream>>>(asum, diffb, act, flags, mxb, asumtot, nanflag);

    P3 pw;
    pw.a[0] = qw;  pw.a[1] = kw;  pw.a[2] = vw;
    pw.b[0] = ipw; pw.b[1] = ipw + 262144; pw.b[2] = ipw + 524288;
    pw.bi[0] = pw.bi[1] = pw.bi[2] = nullptr;
    pw.c[0] = weff; pw.c[1] = weff + 393216; pw.c[2] = weff + 786432;
    gemm64<float, float, float, true, false><<<dim3(12, 8, 3), 256, 0, stream>>>(pw, 768, 512, 512);

    maxscan_f32<<<dim3(256), 256, 0, stream>>>(weff, 1179648, mxb + 4);

    P3 pq;
    pq.a[0] = pq.a[1] = pq.a[2] = emb;
    pq.b[0] = weff; pq.b[1] = weff + 393216; pq.b[2] = weff + 786432;
    pq.bi[0] = ipb; pq.bi[1] = ipb + 512; pq.bi[2] = ipb + 1024;
    pq.c[0] = qh; pq.c[1] = kh; pq.c[2] = vh;
    gemm64<float, float, bf16, false, true><<<dim3(64, 8, 3), 256, 0, stream>>>(pq, 4096, 512, 768);

    maxscan_bf16<<<dim3(512), 256, 0, stream>>>(qkv, 6291456, mxb + 3);
    nanscan_bf16<<<dim3(512), 64, 0, stream>>>((const unsigned short*)qkv, 6291456, nanflag);

    attn_kernel<<<dim3(512), 256, 0, stream>>>(qh, kh, vh, oatt);

    maxscan_bf16<<<dim3(256), 256, 0, stream>>>(oatt, 2097152, mxb + 2);
    nanscan_bf16<<<dim3(256), 64, 0, stream>>>((const unsigned short*)oatt, 2097152, nanflag);

    P3 pt;
    pt.a[0] = oatt; pt.b[0] = ow; pt.bi[0] = ob; pt.c[0] = X;
    pt.a[1] = pt.a[2] = pt.b[1] = pt.b[2] = nullptr;
    pt.bi[1] = pt.bi[2] = nullptr; pt.c[1] = pt.c[2] = nullptr;
    gemm64<bf16, float, float, true, true><<<dim3(64, 8, 1), 256, 0, stream>>>(pt, 4096, 512, 512);

    maxscan_f32<<<dim3(256), 256, 0, stream>>>(X, 2097152, mxb + 0);
    nanscan_f32<<<dim3(256), 64, 0, stream>>>(X, 2097152, nanflag);

    k_xnorm<<<dim3(128), 256, 0, stream>>>(X, xnorm);
    k_gather<<<dim3(64), 256, 0, stream>>>(X, idx, Ctr);
    k_cnorm<<<dim3(32), 256, 0, stream>>>(Ctr, cnorm);

    for (int i = 0; i <= 100; i++) {
        dkm_assign<<<dim3(128), 256, 0, stream>>>(X, xnorm, Ctr, cnorm, a, asum, Cacc, act);
        dkm_reduce<<<dim3(128), 256, 0, stream>>>(Cacc, asum, Ctr, Cnew, diffb, i, act);
        if (i == 0) {
            maxscan_f32<<<dim3(64), 256, 0, stream>>>(Cnew, 16384, mxb + 5);
            maxscan_f32<<<dim3(1), 64, 0, stream>>>(asum, 32, mxb + 6);
        }
        dkm_update<<<dim3(64), 256, 0, stream>>>(Ctr, Cnew, cnorm, asum, diffb, i, act);
    }

    maxscan_f32<<<dim3(64), 256, 0, stream>>>(Ctr, 16384, mxb + 1);
    nanscan_f32<<<dim3(64), 64, 0, stream>>>(Ctr, 16384, nanflag);
    sumscan_f32<<<dim3(128), 256, 0, stream>>>(a, 131072, asumtot);
    nanscan_f32<<<dim3(128), 64, 0, stream>>>(a, 131072, nanflag);

    k_flags<<<1, 64, 0, stream>>>(mxb, asumtot, nanflag, flags);
    out_kernel<<<dim3(576), 256, 0, stream>>>(Ctr, a, flags, out);
}

// Round 10
// 1083.247 us; speedup vs baseline: 1.9314x; 1.9314x over previous
//
#include <hip/hip_runtime.h>
#include <hip/hip_bf16.h>

// MHA (8 heads, N=4096, D=512) + soft k-means (K=32). Round 10: MFMA everywhere
// matmul-shaped (weff/qkv/out-proj GEMMs + flash attention), diagnostics stripped.
// Output format (verified R9): d_out = 4-byte words, bf16 payload in HIGH 16 bits;
// words [0:16384] = C[32,512]; words [16384:147456] = a[4096,32]. DKM unchanged.

typedef __hip_bfloat16 bf16;
typedef __attribute__((ext_vector_type(8))) short s16x8;
typedef __attribute__((ext_vector_type(4))) float f32x4;

__device__ __forceinline__ void  stv(float* p, float v) { *p = v; }
__device__ __forceinline__ void  stv(bf16*  p, float v) { *p = __float2bfloat16(v); }

__device__ __forceinline__ unsigned bf16word(float v)
{
    bf16 b = __float2bfloat16(v);
    unsigned short u;
    __builtin_memcpy(&u, &b, 2);
    return ((unsigned)u) << 16;   // bf16 payload in HIGH 16 bits
}

// stage 8 contiguous elements (converting fp32->bf16 if needed) as one 16B LDS write
__device__ __forceinline__ void stage8(const float* g, bf16* d)
{
    const float4 a = *(const float4*)g;
    const float4 b = *(const float4*)(g + 4);
    union { uint4 u; bf16 h[8]; } r;
    r.h[0] = __float2bfloat16(a.x); r.h[1] = __float2bfloat16(a.y);
    r.h[2] = __float2bfloat16(a.z); r.h[3] = __float2bfloat16(a.w);
    r.h[4] = __float2bfloat16(b.x); r.h[5] = __float2bfloat16(b.y);
    r.h[6] = __float2bfloat16(b.z); r.h[7] = __float2bfloat16(b.w);
    *(uint4*)d = r.u;
}
__device__ __forceinline__ void stage8(const bf16* g, bf16* d)
{
    *(uint4*)d = *(const uint4*)g;
}
__device__ __forceinline__ void load8f(const float* g, float* v)
{
    const float4 a = *(const float4*)g; const float4 b = *(const float4*)(g + 4);
    v[0]=a.x; v[1]=a.y; v[2]=a.z; v[3]=a.w; v[4]=b.x; v[5]=b.y; v[6]=b.z; v[7]=b.w;
}
__device__ __forceinline__ void load8f(const bf16* g, float* v)
{
    union { uint4 u; bf16 h[8]; } r; r.u = *(const uint4*)g;
#pragma unroll
    for (int j = 0; j < 8; j++) v[j] = __bfloat162float(r.h[j]);
}

struct P3 { const void* a[3]; const void* b[3]; const float* bi[3]; void* c[3]; };

// C[M,N] = A[M,K] * op(B) (+bias). BT: B stored [N][K]. MFMA 16x16x32 bf16.
// 64x64 tile, BK=32, 256 thr = 4 waves, wave w owns rows w*16..w*16+15.
template<typename TA, typename TB, typename TC, bool BT, bool BIAS>
__global__ __launch_bounds__(256) void mgemm(P3 p, int M, int N, int K)
{
    __shared__ __align__(16) bf16 As[64][40];   // [m][k] stride 40 (80B: aligned, 2-way)
    __shared__ __align__(16) bf16 Bs[64][40];   // [n][k]
    const int z = blockIdx.z;
    const TA* A = (const TA*)p.a[z];
    const TB* B = (const TB*)p.b[z];
    const float* bias = p.bi[z];
    TC* C = (TC*)p.c[z];
    const int m0 = blockIdx.x * 64, n0 = blockIdx.y * 64;
    const int t = threadIdx.x;
    const int w = t >> 6, lane = t & 63, quad = lane >> 4, l15 = lane & 15;
    f32x4 acc[4];
#pragma unroll
    for (int i = 0; i < 4; i++) acc[i] = (f32x4){0.f, 0.f, 0.f, 0.f};
    for (int k0 = 0; k0 < K; k0 += 32) {
        {   // A: 64x32, 8 elems/thread
            int r = t >> 2, c = (t & 3) * 8;
            stage8(&A[(size_t)(m0 + r) * K + k0 + c], &As[r][c]);
        }
        if constexpr (BT) {
            int r = t >> 2, c = (t & 3) * 8;
            stage8(&B[(size_t)(n0 + r) * K + k0 + c], &Bs[r][c]);
        } else {
            int k = t >> 3, n8 = (t & 7) * 8;
            float v[8];
            load8f(&B[(size_t)(k0 + k) * N + n0 + n8], v);
#pragma unroll
            for (int j = 0; j < 8; j++) Bs[n8 + j][k] = __float2bfloat16(v[j]);
        }
        __syncthreads();
        s16x8 af = *(const s16x8*)&As[w * 16 + l15][quad * 8];
#pragma unroll
        for (int nt = 0; nt < 4; nt++) {
            s16x8 bfv = *(const s16x8*)&Bs[nt * 16 + l15][quad * 8];
            acc[nt] = __builtin_amdgcn_mfma_f32_16x16x32_bf16(af, bfv, acc[nt], 0, 0, 0);
        }
        __syncthreads();
    }
#pragma unroll
    for (int nt = 0; nt < 4; nt++) {
        int col = n0 + nt * 16 + l15;
        float bv = 0.f;
        if constexpr (BIAS) bv = bias[col];
#pragma unroll
        for (int r = 0; r < 4; r++) {
            int row = m0 + w * 16 + quad * 4 + r;
            stv(&C[(size_t)row * N + col], acc[nt][r] + bv);
        }
    }
}

// Flash attention, MFMA. Block = (head, 64 q-rows), 4 waves; wave w owns q-rows w*16..+15.
__global__ __launch_bounds__(256) void attn_mfma(
    const bf16* __restrict__ qh, const bf16* __restrict__ kh,
    const bf16* __restrict__ vh, bf16* __restrict__ oatt)
{
    __shared__ __align__(16) bf16  Qs[64][72];  // [q][d]
    __shared__ __align__(16) bf16  Ks[64][72];  // [k][d]
    __shared__ __align__(16) bf16  Vt[64][72];  // [d][k]  (V transposed)
    __shared__ __align__(16) float Ss[64][68];  // [q][k]  scores -> P
    __shared__ float mrow[64], lrow[64], arow[64];
    const int bid = blockIdx.x;
    const int h = bid & 7, q0 = (bid >> 3) * 64;
    const int t = threadIdx.x;
    const int w = t >> 6, lane = t & 63, quad = lane >> 4, l15 = lane & 15;

#pragma unroll
    for (int i = 0; i < 2; i++) {
        int idx = t + i * 256;
        int r = idx >> 3, c = (idx & 7) * 8;
        *(uint4*)&Qs[r][c] = *(const uint4*)&qh[(size_t)(q0 + r) * 512 + h * 64 + c];
    }
    if (t < 64) { mrow[t] = -1e30f; lrow[t] = 0.f; }
    f32x4 accO[4];
#pragma unroll
    for (int i = 0; i < 4; i++) accO[i] = (f32x4){0.f, 0.f, 0.f, 0.f};

    for (int kb = 0; kb < 4096; kb += 64) {
        __syncthreads();   // previous PV done before restaging K/Vt
#pragma unroll
        for (int i = 0; i < 2; i++) {
            int idx = t + i * 256;
            int r = idx >> 3, c = (idx & 7) * 8;
            *(uint4*)&Ks[r][c] = *(const uint4*)&kh[(size_t)(kb + r) * 512 + h * 64 + c];
            union { uint4 u; bf16 b[8]; } vv;
            vv.u = *(const uint4*)&vh[(size_t)(kb + r) * 512 + h * 64 + c];
#pragma unroll
            for (int j = 0; j < 8; j++) Vt[c + j][r] = vv.b[j];
        }
        __syncthreads();
        // S = (Q K^T) * 0.125
        f32x4 accS[4];
#pragma unroll
        for (int i = 0; i < 4; i++) accS[i] = (f32x4){0.f, 0.f, 0.f, 0.f};
#pragma unroll
        for (int dc = 0; dc < 64; dc += 32) {
            s16x8 aq = *(const s16x8*)&Qs[w * 16 + l15][dc + quad * 8];
#pragma unroll
            for (int nt = 0; nt < 4; nt++) {
                s16x8 bk = *(const s16x8*)&Ks[nt * 16 + l15][dc + quad * 8];
                accS[nt] = __builtin_amdgcn_mfma_f32_16x16x32_bf16(aq, bk, accS[nt], 0, 0, 0);
            }
        }
#pragma unroll
        for (int nt = 0; nt < 4; nt++)
#pragma unroll
            for (int r = 0; r < 4; r++)
                Ss[w * 16 + quad * 4 + r][nt * 16 + l15] = accS[nt][r] * 0.125f;
        __syncthreads();
        if (t < 64) {  // online softmax, one thread per q-row
            float mold = mrow[t];
            float mx = mold;
            for (int kk = 0; kk < 64; kk++) mx = fmaxf(mx, Ss[t][kk]);
            float al = expf(mold - mx);
            float ps = 0.f;
            for (int kk = 0; kk < 64; kk++) {
                float pv = expf(Ss[t][kk] - mx);
                Ss[t][kk] = pv;
                ps += pv;
            }
            lrow[t] = lrow[t] * al + ps;
            mrow[t] = mx;
            arow[t] = al;
        }
        __syncthreads();
        float al4[4];
#pragma unroll
        for (int r = 0; r < 4; r++) al4[r] = arow[w * 16 + quad * 4 + r];
#pragma unroll
        for (int dt = 0; dt < 4; dt++)
#pragma unroll
            for (int r = 0; r < 4; r++) accO[dt][r] *= al4[r];
        // O += P V   (P: A-operand from LDS fp32 -> bf16; V^T: B-operand)
#pragma unroll
        for (int kc = 0; kc < 64; kc += 32) {
            const float* pr = &Ss[w * 16 + l15][kc + quad * 8];
            float4 p0 = *(const float4*)pr;
            float4 p1 = *(const float4*)(pr + 4);
            union { s16x8 v; bf16 h[8]; } pf;
            pf.h[0] = __float2bfloat16(p0.x); pf.h[1] = __float2bfloat16(p0.y);
            pf.h[2] = __float2bfloat16(p0.z); pf.h[3] = __float2bfloat16(p0.w);
            pf.h[4] = __float2bfloat16(p1.x); pf.h[5] = __float2bfloat16(p1.y);
            pf.h[6] = __float2bfloat16(p1.z); pf.h[7] = __float2bfloat16(p1.w);
#pragma unroll
            for (int dt = 0; dt < 4; dt++) {
                s16x8 bv = *(const s16x8*)&Vt[dt * 16 + l15][kc + quad * 8];
                accO[dt] = __builtin_amdgcn_mfma_f32_16x16x32_bf16(pf.v, bv, accO[dt], 0, 0, 0);
            }
        }
    }
#pragma unroll
    for (int dt = 0; dt < 4; dt++)
#pragma unroll
        for (int r = 0; r < 4; r++) {
            int row = w * 16 + quad * 4 + r;
            oatt[(size_t)(q0 + row) * 512 + h * 64 + dt * 16 + l15] =
                __float2bfloat16(accO[dt][r] / lrow[row]);
        }
}

__global__ __launch_bounds__(256) void k_init(float* asum, float* diffb, int* act)
{
    int t = threadIdx.x;
    if (t < 32)  asum[t]  = 0.f;
    if (t < 104) diffb[t] = 0.f;
    if (t == 104) *act = 1;
}

__global__ __launch_bounds__(256) void k_xnorm(const float* __restrict__ X, float* __restrict__ xnorm)
{
    __shared__ float xr[32][9];
    int b = blockIdx.x, t = threadIdx.x;
    int rl = t >> 3, j = t & 7;
    const float* p = X + (size_t)(b * 32 + rl) * 512 + j * 64;
    float s = 0.f;
#pragma unroll
    for (int i = 0; i < 64; i++) { float v = p[i]; s += v * v; }
    xr[rl][j] = s;
    __syncthreads();
    if (t < 32) {
        float tot = 0.f;
#pragma unroll
        for (int jj = 0; jj < 8; jj++) tot += xr[t][jj];
        xnorm[b * 32 + t] = tot;
    }
}

__global__ __launch_bounds__(256) void k_gather(const float* __restrict__ X,
                                                const int* __restrict__ idx, float* __restrict__ Ctr)
{
    int o = blockIdx.x * 256 + threadIdx.x;
    int kk = o & 31, e = o >> 5;
    Ctr[o] = X[(size_t)idx[kk] * 512 + e];
}

__global__ __launch_bounds__(256) void k_cnorm(const float* __restrict__ Ctr, float* __restrict__ cnorm)
{
    __shared__ float red[256];
    int b = blockIdx.x, t = threadIdx.x;
    float s = 0.f;
    for (int e = t; e < 512; e += 256) { float v = Ctr[e * 32 + b]; s += v * v; }
    red[t] = s; __syncthreads();
    for (int st = 128; st > 0; st >>= 1) { if (t < st) red[t] += red[t + st]; __syncthreads(); }
    if (t == 0) cnorm[b] = red[0];
}

__global__ __launch_bounds__(256) void dkm_assign(
    const float* __restrict__ X, const float* __restrict__ xnorm,
    const float* __restrict__ Ctr, const float* __restrict__ cnorm,
    float* __restrict__ a, float* __restrict__ asum, float* __restrict__ Cacc,
    const int* __restrict__ act)
{
    if (*act == 0) return;
    __shared__ float Cs[128][32];
    __shared__ float as_[32][32];
    const int b = blockIdx.x, t = threadIdx.x;
    const int n0 = b * 32;
    const int k = t & 31, rg = t >> 5;
    float dots[4] = {0.f, 0.f, 0.f, 0.f};
    for (int ec = 0; ec < 4; ec++) {
        __syncthreads();
#pragma unroll
        for (int i = 0; i < 16; i++) {
            int idx = t + i * 256;
            Cs[idx >> 5][idx & 31] = Ctr[ec * 4096 + idx];
        }
        __syncthreads();
        const float* xb = X + (size_t)(n0 + rg) * 512 + ec * 128;
#pragma unroll 8
        for (int ee = 0; ee < 128; ee++) {
            float cv = Cs[ee][k];
            dots[0] += xb[ee] * cv;
            dots[1] += xb[8 * 512 + ee] * cv;
            dots[2] += xb[16 * 512 + ee] * cv;
            dots[3] += xb[24 * 512 + ee] * cv;
        }
    }
    float cn = cnorm[k];
#pragma unroll
    for (int rr = 0; rr < 4; rr++) {
        int rl = rg + rr * 8;
        float d2 = xnorm[n0 + rl] + cn - 2.f * dots[rr];
        as_[rl][k] = -2.f * sqrtf(fmaxf(d2, 0.f));
    }
    __syncthreads();
    if (t < 32) {
        float mx = -1e30f;
        for (int kk = 0; kk < 32; kk++) mx = fmaxf(mx, as_[t][kk]);
        float su = 0.f;
        for (int kk = 0; kk < 32; kk++) su += expf(as_[t][kk] - mx);
        float inv = 1.f / su;
        for (int kk = 0; kk < 32; kk++) as_[t][kk] = expf(as_[t][kk] - mx) * inv;
    }
    __syncthreads();
#pragma unroll
    for (int i = 0; i < 4; i++) {
        int o = t + i * 256;
        int r = o >> 5, kk = o & 31;
        a[(size_t)(n0 + r) * 32 + kk] = as_[r][kk];
    }
    if (t < 32) {
        float s = 0.f;
        for (int r = 0; r < 32; r++) s += as_[r][t];
        atomicAdd(&asum[t], s);
    }
    float acc[64];
#pragma unroll
    for (int i = 0; i < 64; i++) acc[i] = 0.f;
    const float2* X2 = (const float2*)(X + (size_t)n0 * 512);
    for (int r = 0; r < 32; r++) {
        float2 xv = X2[r * 256 + t];
        const float4* ar4 = (const float4*)as_[r];
#pragma unroll
        for (int kq = 0; kq < 8; kq++) {
            float4 av = ar4[kq];
            acc[(kq * 4 + 0) * 2 + 0] += av.x * xv.x; acc[(kq * 4 + 0) * 2 + 1] += av.x * xv.y;
            acc[(kq * 4 + 1) * 2 + 0] += av.y * xv.x; acc[(kq * 4 + 1) * 2 + 1] += av.y * xv.y;
            acc[(kq * 4 + 2) * 2 + 0] += av.z * xv.x; acc[(kq * 4 + 2) * 2 + 1] += av.z * xv.y;
            acc[(kq * 4 + 3) * 2 + 0] += av.w * xv.x; acc[(kq * 4 + 3) * 2 + 1] += av.w * xv.y;
        }
    }
    float2* cb = (float2*)(Cacc + (size_t)b * 16384);
#pragma unroll
    for (int k2 = 0; k2 < 32; k2++) {
        float2 wv; wv.x = acc[k2 * 2 + 0]; wv.y = acc[k2 * 2 + 1];
        cb[k2 * 256 + t] = wv;
    }
}

__global__ __launch_bounds__(256) void dkm_reduce(
    const float* __restrict__ Cacc, const float* __restrict__ asum,
    const float* __restrict__ Ctr, float* __restrict__ Cnew,
    float* __restrict__ diffb, int iter, const int* __restrict__ act)
{
    if (*act == 0) return;
    __shared__ float red[256];
    const int b = blockIdx.x, t = threadIdx.x;
    const int j = t & 127, half = t >> 7;
    const int o = b * 128 + j;
    float s = 0.f;
    for (int p = half * 64; p < half * 64 + 64; p++) s += Cacc[(size_t)p * 16384 + o];
    red[t] = s;
    __syncthreads();
    float df = 0.f;
    if (t < 128) {
        float tot = red[t] + red[t + 128];
        int kk = o >> 9, e = o & 511;
        float cn = tot / (asum[kk] + 1e-6f);
        Cnew[e * 32 + kk] = cn;
        df = fabsf(cn - Ctr[e * 32 + kk]);
    }
    __syncthreads();
    red[t] = df;
    __syncthreads();
    for (int st = 128; st > 0; st >>= 1) { if (t < st) red[t] += red[t + st]; __syncthreads(); }
    if (t == 0) atomicAdd(&diffb[iter], red[0]);
}

__global__ __launch_bounds__(256) void dkm_update(
    float* __restrict__ Ctr, const float* __restrict__ Cnew,
    float* __restrict__ cnorm, float* __restrict__ asum,
    const float* __restrict__ diffb, int iter, int* __restrict__ act)
{
    if (*act == 0) return;
    const int b = blockIdx.x, t = threadIdx.x;
    float dv = diffb[iter];
    if (!(dv > 1e-4f)) { if (b == 0 && t == 0) *act = 0; return; }
    if (iter == 100) return;
    __shared__ float red[256];
    if (b < 32) {
        float p = 0.f;
        for (int e = t; e < 512; e += 256) { float v = Cnew[e * 32 + b]; p += v * v; }
        red[t] = p; __syncthreads();
        for (int st = 128; st > 0; st >>= 1) { if (t < st) red[t] += red[t + st]; __syncthreads(); }
        if (t == 0) cnorm[b] = red[0];
    } else {
        int bb = b - 32;
        for (int i = t; i < 512; i += 256) Ctr[bb * 512 + i] = Cnew[bb * 512 + i];
        if (b == 32 && t < 32) asum[t] = 0.f;
    }
}

// d_out = 4-byte words, bf16 payload in HIGH 16 bits.
__global__ __launch_bounds__(256) void out_kernel(
    const float* __restrict__ Ctr, const float* __restrict__ a, unsigned* __restrict__ out)
{
    int idx = blockIdx.x * 256 + threadIdx.x;
    float v;
    if (idx < 16384) {
        int kk = idx >> 9, e = idx & 511;
        v = Ctr[e * 32 + kk];
    } else {
        v = a[idx - 16384];
    }
    out[idx] = bf16word(v);
}

extern "C" void kernel_launch(void* const* d_in, const int* in_sizes, int n_in,
                              void* d_out, int out_size, void* d_ws, size_t ws_size,
                              hipStream_t stream)
{
    const size_t NEED = 26362580;
    if (ws_size < NEED) return;

    const float* emb = (const float*)d_in[0];
    const float* qw  = (const float*)d_in[1];
    const float* kw  = (const float*)d_in[2];
    const float* vw  = (const float*)d_in[3];
    const float* ipw = (const float*)d_in[4];
    const float* ipb = (const float*)d_in[5];
    const float* ow  = (const float*)d_in[6];
    const float* ob  = (const float*)d_in[7];
    const int*   idx = (const int*)d_in[8];
    unsigned* out = (unsigned*)d_out;

    float* ws    = (float*)d_ws;
    bf16*  qkv   = (bf16*)ws;               // [3][4096][512] bf16
    bf16*  weff  = (bf16*)(ws + 3145728);   // [3][768][512] bf16 (589824 float-slots)
    bf16*  oatt  = (bf16*)(ws + 3145728);   // alias weff (dead after qkv gemm)
    float* X     = ws;                      // alias qkv (dead after attn)
    float* a     = ws + 4325376;
    float* Cacc  = ws + 4456448;
    float* xnorm = ws + 6553600;
    float* Ctr   = ws + 6557696;
    float* Cnew  = ws + 6574080;
    float* cnorm = ws + 6590464;
    float* asum  = ws + 6590496;
    float* diffb = ws + 6590528;
    int*   act   = (int*)(ws + 6590632);

    bf16* qh = qkv;
    bf16* kh = qkv + 2097152;
    bf16* vh = qkv + 4194304;

    k_init<<<1, 256, 0, stream>>>(asum, diffb, act);

    // weff_z = zw @ Wz^T  (bf16 out), M=768 N=512 K=512, B=[n][k]
    P3 pw;
    pw.a[0] = qw;  pw.a[1] = kw;  pw.a[2] = vw;
    pw.b[0] = ipw; pw.b[1] = ipw + 262144; pw.b[2] = ipw + 524288;
    pw.bi[0] = pw.bi[1] = pw.bi[2] = nullptr;
    pw.c[0] = weff; pw.c[1] = weff + 393216; pw.c[2] = weff + 786432;
    mgemm<float, float, bf16, true, false><<<dim3(12, 8, 3), 256, 0, stream>>>(pw, 768, 512, 512);

    // qkv_z = emb @ weff_z + bias_z  (bf16 out), M=4096 N=512 K=768, B=[k][n] bf16
    P3 pq;
    pq.a[0] = pq.a[1] = pq.a[2] = emb;
    pq.b[0] = weff; pq.b[1] = weff + 393216; pq.b[2] = weff + 786432;
    pq.bi[0] = ipb; pq.bi[1] = ipb + 512; pq.bi[2] = ipb + 1024;
    pq.c[0] = qh; pq.c[1] = kh; pq.c[2] = vh;
    mgemm<float, bf16, bf16, false, true><<<dim3(64, 8, 3), 256, 0, stream>>>(pq, 4096, 512, 768);

    attn_mfma<<<dim3(512), 256, 0, stream>>>(qh, kh, vh, oatt);

    // X = oatt @ out_w^T + out_b  (fp32 out), M=4096 N=512 K=512, B=[n][k] fp32
    P3 pt;
    pt.a[0] = oatt; pt.b[0] = ow; pt.bi[0] = ob; pt.c[0] = X;
    pt.a[1] = pt.a[2] = pt.b[1] = pt.b[2] = nullptr;
    pt.bi[1] = pt.bi[2] = nullptr; pt.c[1] = pt.c[2] = nullptr;
    mgemm<bf16, float, float, true, true><<<dim3(64, 8, 1), 256, 0, stream>>>(pt, 4096, 512, 512);

    k_xnorm<<<dim3(128), 256, 0, stream>>>(X, xnorm);
    k_gather<<<dim3(64), 256, 0, stream>>>(X, idx, Ctr);
    k_cnorm<<<dim3(32), 256, 0, stream>>>(Ctr, cnorm);

    for (int i = 0; i <= 100; i++) {
        dkm_assign<<<dim3(128), 256, 0, stream>>>(X, xnorm, Ctr, cnorm, a, asum, Cacc, act);
        dkm_reduce<<<dim3(128), 256, 0, stream>>>(Cacc, asum, Ctr, Cnew, diffb, i, act);
        dkm_update<<<dim3(64), 256, 0, stream>>>(Ctr, Cnew, cnorm, asum, diffb, i, act);
    }

    out_kernel<<<dim3(576), 256, 0, stream>>>(Ctr, a, out);
}

// Round 12
// 730.286 us; speedup vs baseline: 2.8649x; 1.4833x over previous
//
#include <hip/hip_runtime.h>
#include <hip/hip_bf16.h>

// MHA (8 heads, N=4096, D=512) + soft k-means (K=32). Round 12: persistent DKM with
// manual software grid barrier (normal launch; hipLaunchCooperativeKernel failed in R11).
// MFMA GEMMs + flash attention unchanged from R10 (verified). 7 launches total.
// Output format (verified R9): d_out = 4-byte words, bf16 payload in HIGH 16 bits;
// words [0:16384] = C[32,512]; words [16384:147456] = a[4096,32].

typedef __hip_bfloat16 bf16;
typedef __attribute__((ext_vector_type(8))) short s16x8;
typedef __attribute__((ext_vector_type(4))) float f32x4;

__device__ __forceinline__ void  stv(float* p, float v) { *p = v; }
__device__ __forceinline__ void  stv(bf16*  p, float v) { *p = __float2bfloat16(v); }

__device__ __forceinline__ unsigned bf16word(float v)
{
    bf16 b = __float2bfloat16(v);
    unsigned short u;
    __builtin_memcpy(&u, &b, 2);
    return ((unsigned)u) << 16;   // bf16 payload in HIGH 16 bits
}

__device__ __forceinline__ void stage8(const float* g, bf16* d)
{
    const float4 a = *(const float4*)g;
    const float4 b = *(const float4*)(g + 4);
    union { uint4 u; bf16 h[8]; } r;
    r.h[0] = __float2bfloat16(a.x); r.h[1] = __float2bfloat16(a.y);
    r.h[2] = __float2bfloat16(a.z); r.h[3] = __float2bfloat16(a.w);
    r.h[4] = __float2bfloat16(b.x); r.h[5] = __float2bfloat16(b.y);
    r.h[6] = __float2bfloat16(b.z); r.h[7] = __float2bfloat16(b.w);
    *(uint4*)d = r.u;
}
__device__ __forceinline__ void stage8(const bf16* g, bf16* d)
{
    *(uint4*)d = *(const uint4*)g;
}
__device__ __forceinline__ void load8f(const float* g, float* v)
{
    const float4 a = *(const float4*)g; const float4 b = *(const float4*)(g + 4);
    v[0]=a.x; v[1]=a.y; v[2]=a.z; v[3]=a.w; v[4]=b.x; v[5]=b.y; v[6]=b.z; v[7]=b.w;
}
__device__ __forceinline__ void load8f(const bf16* g, float* v)
{
    union { uint4 u; bf16 h[8]; } r; r.u = *(const uint4*)g;
#pragma unroll
    for (int j = 0; j < 8; j++) v[j] = __bfloat162float(r.h[j]);
}

struct P3 { const void* a[3]; const void* b[3]; const float* bi[3]; void* c[3]; };

template<typename TA, typename TB, typename TC, bool BT, bool BIAS>
__global__ __launch_bounds__(256) void mgemm(P3 p, int M, int N, int K)
{
    __shared__ __align__(16) bf16 As[64][40];
    __shared__ __align__(16) bf16 Bs[64][40];
    const int z = blockIdx.z;
    const TA* A = (const TA*)p.a[z];
    const TB* B = (const TB*)p.b[z];
    const float* bias = p.bi[z];
    TC* C = (TC*)p.c[z];
    const int m0 = blockIdx.x * 64, n0 = blockIdx.y * 64;
    const int t = threadIdx.x;
    const int w = t >> 6, lane = t & 63, quad = lane >> 4, l15 = lane & 15;
    f32x4 acc[4];
#pragma unroll
    for (int i = 0; i < 4; i++) acc[i] = (f32x4){0.f, 0.f, 0.f, 0.f};
    for (int k0 = 0; k0 < K; k0 += 32) {
        {
            int r = t >> 2, c = (t & 3) * 8;
            stage8(&A[(size_t)(m0 + r) * K + k0 + c], &As[r][c]);
        }
        if constexpr (BT) {
            int r = t >> 2, c = (t & 3) * 8;
            stage8(&B[(size_t)(n0 + r) * K + k0 + c], &Bs[r][c]);
        } else {
            int k = t >> 3, n8 = (t & 7) * 8;
            float v[8];
            load8f(&B[(size_t)(k0 + k) * N + n0 + n8], v);
#pragma unroll
            for (int j = 0; j < 8; j++) Bs[n8 + j][k] = __float2bfloat16(v[j]);
        }
        __syncthreads();
        s16x8 af = *(const s16x8*)&As[w * 16 + l15][quad * 8];
#pragma unroll
        for (int nt = 0; nt < 4; nt++) {
            s16x8 bfv = *(const s16x8*)&Bs[nt * 16 + l15][quad * 8];
            acc[nt] = __builtin_amdgcn_mfma_f32_16x16x32_bf16(af, bfv, acc[nt], 0, 0, 0);
        }
        __syncthreads();
    }
#pragma unroll
    for (int nt = 0; nt < 4; nt++) {
        int col = n0 + nt * 16 + l15;
        float bv = 0.f;
        if constexpr (BIAS) bv = bias[col];
#pragma unroll
        for (int r = 0; r < 4; r++) {
            int row = m0 + w * 16 + quad * 4 + r;
            stv(&C[(size_t)row * N + col], acc[nt][r] + bv);
        }
    }
}

__global__ __launch_bounds__(256) void attn_mfma(
    const bf16* __restrict__ qh, const bf16* __restrict__ kh,
    const bf16* __restrict__ vh, bf16* __restrict__ oatt)
{
    __shared__ __align__(16) bf16  Qs[64][72];
    __shared__ __align__(16) bf16  Ks[64][72];
    __shared__ __align__(16) bf16  Vt[64][72];
    __shared__ __align__(16) float Ss[64][68];
    __shared__ float mrow[64], lrow[64], arow[64];
    const int bid = blockIdx.x;
    const int h = bid & 7, q0 = (bid >> 3) * 64;
    const int t = threadIdx.x;
    const int w = t >> 6, lane = t & 63, quad = lane >> 4, l15 = lane & 15;

#pragma unroll
    for (int i = 0; i < 2; i++) {
        int idx = t + i * 256;
        int r = idx >> 3, c = (idx & 7) * 8;
        *(uint4*)&Qs[r][c] = *(const uint4*)&qh[(size_t)(q0 + r) * 512 + h * 64 + c];
    }
    if (t < 64) { mrow[t] = -1e30f; lrow[t] = 0.f; }
    f32x4 accO[4];
#pragma unroll
    for (int i = 0; i < 4; i++) accO[i] = (f32x4){0.f, 0.f, 0.f, 0.f};

    for (int kb = 0; kb < 4096; kb += 64) {
        __syncthreads();
#pragma unroll
        for (int i = 0; i < 2; i++) {
            int idx = t + i * 256;
            int r = idx >> 3, c = (idx & 7) * 8;
            *(uint4*)&Ks[r][c] = *(const uint4*)&kh[(size_t)(kb + r) * 512 + h * 64 + c];
            union { uint4 u; bf16 b[8]; } vv;
            vv.u = *(const uint4*)&vh[(size_t)(kb + r) * 512 + h * 64 + c];
#pragma unroll
            for (int j = 0; j < 8; j++) Vt[c + j][r] = vv.b[j];
        }
        __syncthreads();
        f32x4 accS[4];
#pragma unroll
        for (int i = 0; i < 4; i++) accS[i] = (f32x4){0.f, 0.f, 0.f, 0.f};
#pragma unroll
        for (int dc = 0; dc < 64; dc += 32) {
            s16x8 aq = *(const s16x8*)&Qs[w * 16 + l15][dc + quad * 8];
#pragma unroll
            for (int nt = 0; nt < 4; nt++) {
                s16x8 bk = *(const s16x8*)&Ks[nt * 16 + l15][dc + quad * 8];
                accS[nt] = __builtin_amdgcn_mfma_f32_16x16x32_bf16(aq, bk, accS[nt], 0, 0, 0);
            }
        }
#pragma unroll
        for (int nt = 0; nt < 4; nt++)
#pragma unroll
            for (int r = 0; r < 4; r++)
                Ss[w * 16 + quad * 4 + r][nt * 16 + l15] = accS[nt][r] * 0.125f;
        __syncthreads();
        if (t < 64) {
            float mold = mrow[t];
            float mx = mold;
            for (int kk = 0; kk < 64; kk++) mx = fmaxf(mx, Ss[t][kk]);
            float al = expf(mold - mx);
            float ps = 0.f;
            for (int kk = 0; kk < 64; kk++) {
                float pv = expf(Ss[t][kk] - mx);
                Ss[t][kk] = pv;
                ps += pv;
            }
            lrow[t] = lrow[t] * al + ps;
            mrow[t] = mx;
            arow[t] = al;
        }
        __syncthreads();
        float al4[4];
#pragma unroll
        for (int r = 0; r < 4; r++) al4[r] = arow[w * 16 + quad * 4 + r];
#pragma unroll
        for (int dt = 0; dt < 4; dt++)
#pragma unroll
            for (int r = 0; r < 4; r++) accO[dt][r] *= al4[r];
#pragma unroll
        for (int kc = 0; kc < 64; kc += 32) {
            const float* pr = &Ss[w * 16 + l15][kc + quad * 8];
            float4 p0 = *(const float4*)pr;
            float4 p1 = *(const float4*)(pr + 4);
            union { s16x8 v; bf16 h[8]; } pf;
            pf.h[0] = __float2bfloat16(p0.x); pf.h[1] = __float2bfloat16(p0.y);
            pf.h[2] = __float2bfloat16(p0.z); pf.h[3] = __float2bfloat16(p0.w);
            pf.h[4] = __float2bfloat16(p1.x); pf.h[5] = __float2bfloat16(p1.y);
            pf.h[6] = __float2bfloat16(p1.z); pf.h[7] = __float2bfloat16(p1.w);
#pragma unroll
            for (int dt = 0; dt < 4; dt++) {
                s16x8 bv = *(const s16x8*)&Vt[dt * 16 + l15][kc + quad * 8];
                accO[dt] = __builtin_amdgcn_mfma_f32_16x16x32_bf16(pf.v, bv, accO[dt], 0, 0, 0);
            }
        }
    }
#pragma unroll
    for (int dt = 0; dt < 4; dt++)
#pragma unroll
        for (int r = 0; r < 4; r++) {
            int row = w * 16 + quad * 4 + r;
            oatt[(size_t)(q0 + row) * 512 + h * 64 + dt * 16 + l15] =
                __float2bfloat16(accO[dt][r] / lrow[row]);
        }
}

__global__ __launch_bounds__(64) void k_bar_init(unsigned* cnt, unsigned* gen)
{
    if (threadIdx.x == 0) { *cnt = 0u; *gen = 0u; }
}

// software grid barrier: generation counter + device atomics + threadfence
__device__ __forceinline__ void gridbar(unsigned* cnt, unsigned* gen)
{
    __syncthreads();
    if (threadIdx.x == 0) {
        __threadfence();                               // release: flush my writes
        unsigned g = atomicAdd(gen, 0u);
        if (atomicAdd(cnt, 1u) == gridDim.x - 1) {
            atomicExch(cnt, 0u);
            __threadfence();
            atomicAdd(gen, 1u);
        } else {
            while (atomicAdd(gen, 0u) == g) __builtin_amdgcn_s_sleep(2);
        }
        __threadfence();                               // acquire: invalidate my caches
    }
    __syncthreads();
}

// persistent DKM: 128 blocks x 256 threads, normal launch, 2 barriers/iteration.
// C ping-pong (Cb0/Cb1); per-iteration slots asumb[101][32], diffb[101], cnormb[102][32].
// Writes a into out every assign; writes final C at the end.
__global__ __launch_bounds__(256) void dkm_persist(
    const float* __restrict__ X, const int* __restrict__ idxp,
    float* __restrict__ Cacc, float* __restrict__ Cb0, float* __restrict__ Cb1,
    float* __restrict__ asumb, float* __restrict__ diffb, float* __restrict__ cnormb,
    unsigned* cnt, unsigned* gen, unsigned* __restrict__ out)
{
    const int b = blockIdx.x, t = threadIdx.x;
    const int n0 = b * 32;
    __shared__ float Cs[128][32];
    __shared__ float as_[32][32];
    __shared__ float red[256];
    __shared__ float xn[32];

    // phase 0: xnorm (LDS-persistent), gather C0, zero per-iteration slots
    {
        int rl = t >> 3, j = t & 7;
        const float* p = X + (size_t)(n0 + rl) * 512 + j * 64;
        float s = 0.f;
#pragma unroll
        for (int i = 0; i < 64; i++) { float v = p[i]; s += v * v; }
        as_[rl][j] = s;
        __syncthreads();
        if (t < 32) {
            float tot = 0.f;
#pragma unroll
            for (int jj = 0; jj < 8; jj++) tot += as_[t][jj];
            xn[t] = tot;
        }
        if (t < 128) {
            int o = b * 128 + t;             // o = e*32+k
            Cb0[o] = X[(size_t)idxp[o & 31] * 512 + (o >> 5)];
        }
        int z = b * 256 + t;
        if (z < 3232) asumb[z] = 0.f;
        if (z < 101)  diffb[z] = 0.f;
        if (z < 3264) cnormb[z] = 0.f;
    }
    gridbar(cnt, gen);
    if (b < 32) {   // cnorm of C0 (plain store into cnormb[0][b])
        float s = 0.f;
        for (int e = t; e < 512; e += 256) { float v = Cb0[e * 32 + b]; s += v * v; }
        red[t] = s; __syncthreads();
        for (int st = 128; st > 0; st >>= 1) { if (t < st) red[t] += red[t + st]; __syncthreads(); }
        if (t == 0) cnormb[b] = red[0];
    }
    gridbar(cnt, gen);

    const int k = t & 31, rg = t >> 5;
    int ifin = 100;
    for (int i = 0; i <= 100; i++) {
        const float* Cc = (i & 1) ? Cb1 : Cb0;
        float* Cn = (i & 1) ? Cb0 : Cb1;
        // ---- assign ----
        float dots[4] = {0.f, 0.f, 0.f, 0.f};
        for (int ec = 0; ec < 4; ec++) {
            __syncthreads();
#pragma unroll
            for (int i2 = 0; i2 < 16; i2++) {
                int idx = t + i2 * 256;
                Cs[idx >> 5][idx & 31] = Cc[ec * 4096 + idx];
            }
            __syncthreads();
            const float* xb = X + (size_t)(n0 + rg) * 512 + ec * 128;
#pragma unroll 8
            for (int ee = 0; ee < 128; ee++) {
                float cv = Cs[ee][k];
                dots[0] += xb[ee] * cv;
                dots[1] += xb[8 * 512 + ee] * cv;
                dots[2] += xb[16 * 512 + ee] * cv;
                dots[3] += xb[24 * 512 + ee] * cv;
            }
        }
        float cn = cnormb[i * 32 + k];
#pragma unroll
        for (int rr = 0; rr < 4; rr++) {
            int rl = rg + rr * 8;
            float d2 = xn[rl] + cn - 2.f * dots[rr];
            as_[rl][k] = -2.f * sqrtf(fmaxf(d2, 0.f));   // -d/TEMP, TEMP=0.5
        }
        __syncthreads();
        if (t < 32) {   // softmax per row
            float mx = -1e30f;
            for (int kk = 0; kk < 32; kk++) mx = fmaxf(mx, as_[t][kk]);
            float su = 0.f;
            for (int kk = 0; kk < 32; kk++) su += expf(as_[t][kk] - mx);
            float inv = 1.f / su;
            for (int kk = 0; kk < 32; kk++) as_[t][kk] = expf(as_[t][kk] - mx) * inv;
        }
        __syncthreads();
#pragma unroll
        for (int i2 = 0; i2 < 4; i2++) {   // a -> out (bf16 words), own rows only
            int o = t + i2 * 256;
            int r = o >> 5, kk = o & 31;
            out[16384 + (n0 + r) * 32 + kk] = bf16word(as_[r][kk]);
        }
        if (i == 100) break;               // step 100: keep Cc, a(Cc)
        if (t < 32) {
            float s = 0.f;
            for (int r = 0; r < 32; r++) s += as_[r][t];
            atomicAdd(&asumb[i * 32 + t], s);
        }
        {   // local a^T X partials
            float acc[64];
#pragma unroll
            for (int i2 = 0; i2 < 64; i2++) acc[i2] = 0.f;
            const float2* X2 = (const float2*)(X + (size_t)n0 * 512);
            for (int r = 0; r < 32; r++) {
                float2 xv = X2[r * 256 + t];
                const float4* ar4 = (const float4*)as_[r];
#pragma unroll
                for (int kq = 0; kq < 8; kq++) {
                    float4 av = ar4[kq];
                    acc[(kq * 4 + 0) * 2 + 0] += av.x * xv.x; acc[(kq * 4 + 0) * 2 + 1] += av.x * xv.y;
                    acc[(kq * 4 + 1) * 2 + 0] += av.y * xv.x; acc[(kq * 4 + 1) * 2 + 1] += av.y * xv.y;
                    acc[(kq * 4 + 2) * 2 + 0] += av.z * xv.x; acc[(kq * 4 + 2) * 2 + 1] += av.z * xv.y;
                    acc[(kq * 4 + 3) * 2 + 0] += av.w * xv.x; acc[(kq * 4 + 3) * 2 + 1] += av.w * xv.y;
                }
            }
            float2* cb = (float2*)(Cacc + (size_t)b * 16384);
#pragma unroll
            for (int k2 = 0; k2 < 32; k2++) {
                float2 wv; wv.x = acc[k2 * 2 + 0]; wv.y = acc[k2 * 2 + 1];
                cb[k2 * 256 + t] = wv;
            }
        }
        gridbar(cnt, gen);
        // ---- reduce: Cn, diffb[i], cnormb[i+1] ----
        {
            const int j = t & 127, half = t >> 7;
            const int o = b * 128 + j;       // o = k*512+e ; block covers kk = b>>2
            float s = 0.f;
            for (int p = half * 64; p < half * 64 + 64; p++) s += Cacc[(size_t)p * 16384 + o];
            red[t] = s;
            __syncthreads();
            float df = 0.f, cp = 0.f;
            if (t < 128) {
                float tot = red[t] + red[t + 128];
                int kk = o >> 9, e = o & 511;
                float cn2 = tot / (asumb[i * 32 + kk] + 1e-6f);
                Cn[e * 32 + kk] = cn2;
                df = fabsf(cn2 - Cc[e * 32 + kk]);
                cp = cn2 * cn2;
            }
            __syncthreads();
            red[t] = df; __syncthreads();
            for (int st = 128; st > 0; st >>= 1) { if (t < st) red[t] += red[t + st]; __syncthreads(); }
            if (t == 0) atomicAdd(&diffb[i], red[0]);
            __syncthreads();
            red[t] = cp; __syncthreads();
            for (int st = 128; st > 0; st >>= 1) { if (t < st) red[t] += red[t + st]; __syncthreads(); }
            if (t == 0) atomicAdd(&cnormb[(i + 1) * 32 + (b >> 2)], red[0]);
        }
        gridbar(cnt, gen);
        if (!(diffb[i] > 1e-4f)) { ifin = i; break; }   // converged: keep Cc, a
    }
    // final C -> out
    {
        const float* Cf = (ifin & 1) ? Cb1 : Cb0;
        if (t < 128) {
            int idx = b * 128 + t;          // idx = kk*512 + e
            int kk = idx >> 9, e = idx & 511;
            out[idx] = bf16word(Cf[e * 32 + kk]);
        }
    }
}

extern "C" void kernel_launch(void* const* d_in, const int* in_sizes, int n_in,
                              void* d_out, int out_size, void* d_ws, size_t ws_size,
                              hipStream_t stream)
{
    const size_t NEED = 25323292;
    if (ws_size < NEED) return;

    const float* emb = (const float*)d_in[0];
    const float* qw  = (const float*)d_in[1];
    const float* kw  = (const float*)d_in[2];
    const float* vw  = (const float*)d_in[3];
    const float* ipw = (const float*)d_in[4];
    const float* ipb = (const float*)d_in[5];
    const float* ow  = (const float*)d_in[6];
    const float* ob  = (const float*)d_in[7];
    const int*   idx = (const int*)d_in[8];
    unsigned* out = (unsigned*)d_out;

    float* ws    = (float*)d_ws;
    bf16*  qkv   = (bf16*)ws;               // [3][4096][512] bf16  (0..3145728 fp-slots)
    bf16*  weff  = (bf16*)(ws + 3145728);   // [3][768][512] bf16
    bf16*  oatt  = (bf16*)(ws + 3145728);   // alias weff (dead after qkv gemm)
    float* X     = ws;                      // alias qkv (dead after attn)
    float* Cacc  = ws + 4194304;            // 2,097,152
    float* Cb0   = ws + 6291456;            // 16384
    float* Cb1   = ws + 6307840;            // 16384
    float* asumb = ws + 6324224;            // 101*32
    float* diffb = ws + 6327456;            // 101
    float* cnormb= ws + 6327557;            // 102*32
    unsigned* cnt = (unsigned*)(ws + 6330821);
    unsigned* gen = (unsigned*)(ws + 6330822);

    bf16* qh = qkv;
    bf16* kh = qkv + 2097152;
    bf16* vh = qkv + 4194304;

    k_bar_init<<<1, 64, 0, stream>>>(cnt, gen);

    // weff_z = zw @ Wz^T
    P3 pw;
    pw.a[0] = qw;  pw.a[1] = kw;  pw.a[2] = vw;
    pw.b[0] = ipw; pw.b[1] = ipw + 262144; pw.b[2] = ipw + 524288;
    pw.bi[0] = pw.bi[1] = pw.bi[2] = nullptr;
    pw.c[0] = weff; pw.c[1] = weff + 393216; pw.c[2] = weff + 786432;
    mgemm<float, float, bf16, true, false><<<dim3(12, 8, 3), 256, 0, stream>>>(pw, 768, 512, 512);

    // qkv_z = emb @ weff_z + bias_z
    P3 pq;
    pq.a[0] = pq.a[1] = pq.a[2] = emb;
    pq.b[0] = weff; pq.b[1] = weff + 393216; pq.b[2] = weff + 786432;
    pq.bi[0] = ipb; pq.bi[1] = ipb + 512; pq.bi[2] = ipb + 1024;
    pq.c[0] = qh; pq.c[1] = kh; pq.c[2] = vh;
    mgemm<float, bf16, bf16, false, true><<<dim3(64, 8, 3), 256, 0, stream>>>(pq, 4096, 512, 768);

    attn_mfma<<<dim3(512), 256, 0, stream>>>(qh, kh, vh, oatt);

    // X = oatt @ out_w^T + out_b
    P3 pt;
    pt.a[0] = oatt; pt.b[0] = ow; pt.bi[0] = ob; pt.c[0] = X;
    pt.a[1] = pt.a[2] = pt.b[1] = pt.b[2] = nullptr;
    pt.bi[1] = pt.bi[2] = nullptr; pt.c[1] = pt.c[2] = nullptr;
    mgemm<bf16, float, float, true, true><<<dim3(64, 8, 1), 256, 0, stream>>>(pt, 4096, 512, 512);

    dkm_persist<<<dim3(128), 256, 0, stream>>>(X, idx, Cacc, Cb0, Cb1,
                                               asumb, diffb, cnormb, cnt, gen, out);
}